// Round 1
// baseline (358.371 us; speedup 1.0000x reference)
//
#include <hip/hip_runtime.h>
#include <math.h>

#define B 1024
#define C 100000
#define D 64
#define TB 128
#define TC 128
#define NCHUNK ((C + TC - 1) / TC)   // 782
#define NRT (B / TB)                 // 8

// ws layout (floats):
//   [0, B*NCHUNK*2)                : (m,s) partials as float2, [row*NCHUNK + chunk]
//   [B*NCHUNK*2, +B)               : d_pos[row]
//   [B*NCHUNK*2 + B, +B)           : per_sample[row]

__global__ __launch_bounds__(256, 1) void proxynca_main(
    const float* __restrict__ xs, const int* __restrict__ ys,
    const float* __restrict__ proxies, float* __restrict__ ws)
{
    __shared__ float As[TB * 64];   // xs tile, swizzled row-major
    __shared__ float Ps[TC * 64];   // normalized proxy tile, swizzled row-major
    __shared__ float xsq[TB];
    __shared__ float psq[TC];
    __shared__ int   ysL[TB];

    const int t = threadIdx.x;            // 0..255
    const int rt = blockIdx.x;            // 0..7   (row tile)
    const int ct = blockIdx.y;            // 0..781 (class chunk)
    const int row0 = rt * TB;
    const int col0 = ct * TC;

    // ---- stage xs tile (coalesced float4, fused x^2 row-reduce via 16-lane shuffles) ----
    #pragma unroll
    for (int j = 0; j < 8; ++j) {
        int idx = j * 256 + t;
        int r  = idx >> 4;                // local row 0..127
        int kq = idx & 15;                // float4 index 0..15
        const float4 v = *(const float4*)(xs + (size_t)(row0 + r) * D + kq * 4);
        float ss = v.x*v.x + v.y*v.y + v.z*v.z + v.w*v.w;
        ss += __shfl_xor(ss, 1);
        ss += __shfl_xor(ss, 2);
        ss += __shfl_xor(ss, 4);
        ss += __shfl_xor(ss, 8);
        int c4 = (kq + (r >> 3)) & 15;    // xor/rotate swizzle at float4 granularity
        *(float4*)(As + r * 64 + c4 * 4) = v;
        if ((t & 15) == 0) xsq[r] = ss;
    }

    // ---- stage proxy tile, L2-normalized in flight ----
    #pragma unroll
    for (int j = 0; j < 8; ++j) {
        int idx = j * 256 + t;
        int r  = idx >> 4;
        int kq = idx & 15;
        int gc = col0 + r;
        int src = gc < C ? gc : (C - 1);  // clamp; masked in epilogue
        const float4 v = *(const float4*)(proxies + (size_t)src * D + kq * 4);
        float ss = v.x*v.x + v.y*v.y + v.z*v.z + v.w*v.w;
        ss += __shfl_xor(ss, 1);
        ss += __shfl_xor(ss, 2);
        ss += __shfl_xor(ss, 4);
        ss += __shfl_xor(ss, 8);
        float rn = 1.0f / fmaxf(sqrtf(ss), 1e-12f);
        float4 w; w.x = v.x*rn; w.y = v.y*rn; w.z = v.z*rn; w.w = v.w*rn;
        int c4 = (kq + (r >> 3)) & 15;
        *(float4*)(Ps + r * 64 + c4 * 4) = w;
        if ((t & 15) == 0) psq[r] = ss * rn * rn;
    }
    if (t < TB) ysL[t] = ys[row0 + t];
    __syncthreads();

    // ---- register-tiled 8x8 fp32 GEMM fragment ----
    const int tx = t & 15;                // class group
    const int ty = t >> 4;                // row group
    float acc[8][8];
    #pragma unroll
    for (int r = 0; r < 8; ++r)
        #pragma unroll
        for (int u = 0; u < 8; ++u) acc[r][u] = 0.f;

    #pragma unroll 2
    for (int kq = 0; kq < 16; ++kq) {
        float4 af[8], bf[8];
        const int ca = ((kq + ty) & 15) * 4;   // i>>3 == ty for all 8 rows
        const int cb = ((kq + tx) & 15) * 4;
        #pragma unroll
        for (int r = 0; r < 8; ++r)
            af[r] = *(const float4*)(As + (ty * 8 + r) * 64 + ca);
        #pragma unroll
        for (int u = 0; u < 8; ++u)
            bf[u] = *(const float4*)(Ps + (tx * 8 + u) * 64 + cb);
        #pragma unroll
        for (int r = 0; r < 8; ++r)
            #pragma unroll
            for (int u = 0; u < 8; ++u) {
                acc[r][u] += af[r].x * bf[u].x;
                acc[r][u] += af[r].y * bf[u].y;
                acc[r][u] += af[r].z * bf[u].z;
                acc[r][u] += af[r].w * bf[u].w;
            }
    }

    // ---- epilogue: dist, d_pos capture, per-row online (m,s) over this chunk ----
    float2* partial = (float2*)ws;
    float*  d_pos   = ws + (size_t)B * NCHUNK * 2;

    #pragma unroll
    for (int r = 0; r < 8; ++r) {
        const int li = ty * 8 + r;
        const int gi = row0 + li;
        const float xq = xsq[li];
        const int yv = ysL[li];

        float lg[8];
        bool  val[8];
        #pragma unroll
        for (int u = 0; u < 8; ++u) {
            const int gc = col0 + tx * 8 + u;
            const float dist = fmaxf(xq + psq[tx * 8 + u] - 2.0f * acc[r][u], 0.f);
            val[u] = (gc < C);
            if (val[u] && gc == yv) {
                d_pos[gi] = dist;
                val[u] = false;          // positive excluded from neg-logsumexp
            }
            lg[u] = -dist;
        }
        float m = -1e30f;
        #pragma unroll
        for (int u = 0; u < 8; ++u) if (val[u]) m = fmaxf(m, lg[u]);
        float s = 0.f;
        #pragma unroll
        for (int u = 0; u < 8; ++u) if (val[u]) s += __expf(lg[u] - m);

        // combine across the 16 class-lanes (consecutive lanes, xor<16 stays in group)
        #pragma unroll
        for (int off = 1; off < 16; off <<= 1) {
            float mo = __shfl_xor(m, off);
            float so = __shfl_xor(s, off);
            float mn = fmaxf(m, mo);
            s = s * __expf(m - mn) + so * __expf(mo - mn);
            m = mn;
        }
        if (tx == 0)
            partial[(size_t)gi * NCHUNK + ct] = make_float2(m, s);
    }
}

__global__ __launch_bounds__(256) void proxynca_reduce(
    const float* __restrict__ ws, float* __restrict__ ps_out)
{
    const int lane = threadIdx.x & 63;
    const int w = threadIdx.x >> 6;
    const int row = blockIdx.x * 4 + w;
    const float2* partial = (const float2*)ws;
    const float* d_pos = ws + (size_t)B * NCHUNK * 2;

    float m = -1e30f, s = 0.f;
    for (int j = lane; j < NCHUNK; j += 64) {
        float2 p = partial[(size_t)row * NCHUNK + j];
        float mn = fmaxf(m, p.x);
        s = s * __expf(m - mn) + p.y * __expf(p.x - mn);
        m = mn;
    }
    #pragma unroll
    for (int off = 1; off < 64; off <<= 1) {
        float mo = __shfl_xor(m, off);
        float so = __shfl_xor(s, off);
        float mn = fmaxf(m, mo);
        s = s * __expf(m - mn) + so * __expf(mo - mn);
        m = mn;
    }
    if (lane == 0) {
        float log_n = m + logf(s);
        ps_out[row] = d_pos[row] + log_n;
    }
}

__global__ __launch_bounds__(1024) void proxynca_final(
    const float* __restrict__ ps, float* __restrict__ out)
{
    __shared__ float red[16];
    const int t = threadIdx.x;
    float v = ps[t];
    #pragma unroll
    for (int off = 1; off < 64; off <<= 1) v += __shfl_xor(v, off);
    if ((t & 63) == 0) red[t >> 6] = v;
    __syncthreads();
    if (t < 16) {
        float x = red[t];
        #pragma unroll
        for (int off = 1; off < 16; off <<= 1) x += __shfl_xor(x, off);
        if (t == 0) out[0] = x * (1.0f / B);
    }
}

extern "C" void kernel_launch(void* const* d_in, const int* in_sizes, int n_in,
                              void* d_out, int out_size, void* d_ws, size_t ws_size,
                              hipStream_t stream)
{
    const float* xs      = (const float*)d_in[0];
    const int*   ys      = (const int*)d_in[1];
    const float* proxies = (const float*)d_in[2];
    float* ws  = (float*)d_ws;
    float* out = (float*)d_out;
    float* ps  = ws + (size_t)B * NCHUNK * 2 + B;   // per_sample

    dim3 gridA(NRT, NCHUNK);
    proxynca_main<<<gridA, 256, 0, stream>>>(xs, ys, proxies, ws);
    proxynca_reduce<<<B / 4, 256, 0, stream>>>(ws, ps);
    proxynca_final<<<1, 1024, 0, stream>>>(ps, out);
}

// Round 2
// 147.058 us; speedup vs baseline: 2.4369x; 2.4369x over previous
//
#include <hip/hip_runtime.h>
#include <math.h>

#define B 1024
#define C 100000
#define D 64
#define MT 128                 // rows per block
#define TC 256                 // classes per block
#define NCH 391                // ceil(C/TC); NCH*TC = 100096
#define CPAD 96                // padded (invalid) classes, staged as zero rows
#define PPR (NCH * 4)          // s-partials per row (4 n-group waves per chunk) = 1564
#define LDA 72                 // LDS row stride (bf16 elems): 144 B, 16B-aligned
#define LDB 72

typedef __attribute__((ext_vector_type(8))) short short8;
typedef __attribute__((ext_vector_type(4))) float f32x4;

static __device__ __forceinline__ unsigned short f2bf(float f) {
    unsigned u = __float_as_uint(f);
    return (unsigned short)((u + 0x7fffu + ((u >> 16) & 1u)) >> 16);  // RNE
}
static __device__ __forceinline__ float bf_round(float f) {
    return __uint_as_float(((unsigned)f2bf(f)) << 16);
}

// ws layout (floats): [0, B*PPR) s-partials [row][part]; [B*PPR, +B) per_sample

__global__ __launch_bounds__(512, 4) void proxynca_main(
    const float* __restrict__ xs, const float* __restrict__ proxies,
    float* __restrict__ ws)
{
    __shared__ unsigned short Ash[MT * LDA];   // xs tile, bf16
    __shared__ unsigned short Bsh[TC * LDB];   // normalized proxies, bf16
    __shared__ float crow[MT];                 // -2*||x_row||

    const int t = threadIdx.x;                 // 0..511
    const int rt = blockIdx.x;                 // 0..7
    const int ct = blockIdx.y;                 // 0..390
    const int row0 = rt * MT;
    const int col0 = ct * TC;

    // ---- stage A (xs) as bf16; fused ||x||^2 via 16-lane shuffles ----
    #pragma unroll
    for (int i = 0; i < 4; ++i) {
        int idx = i * 512 + t;
        int r  = idx >> 4;                     // 0..127
        int f4 = idx & 15;
        const float4 v = *(const float4*)(xs + (size_t)(row0 + r) * D + f4 * 4);
        float ss = v.x*v.x + v.y*v.y + v.z*v.z + v.w*v.w;
        ss += __shfl_xor(ss, 1); ss += __shfl_xor(ss, 2);
        ss += __shfl_xor(ss, 4); ss += __shfl_xor(ss, 8);
        ushort4 w; w.x = f2bf(v.x); w.y = f2bf(v.y); w.z = f2bf(v.z); w.w = f2bf(v.w);
        *(ushort4*)(Ash + r * LDA + f4 * 4) = w;
        if ((t & 15) == 0) crow[r] = -2.0f * sqrtf(ss);
    }

    // ---- stage B (proxies), L2-normalized in flight, bf16; pad classes -> 0 ----
    #pragma unroll
    for (int i = 0; i < 8; ++i) {
        int idx = i * 512 + t;
        int r  = idx >> 4;                     // 0..255
        int f4 = idx & 15;
        int gc = col0 + r;
        int src = gc < C ? gc : (C - 1);
        float4 v = *(const float4*)(proxies + (size_t)src * D + f4 * 4);
        if (gc >= C) { v.x = 0.f; v.y = 0.f; v.z = 0.f; v.w = 0.f; }
        float ss = v.x*v.x + v.y*v.y + v.z*v.z + v.w*v.w;
        ss += __shfl_xor(ss, 1); ss += __shfl_xor(ss, 2);
        ss += __shfl_xor(ss, 4); ss += __shfl_xor(ss, 8);
        float rn = 1.0f / fmaxf(sqrtf(ss), 1e-12f);
        ushort4 w;
        w.x = f2bf(v.x * rn); w.y = f2bf(v.y * rn);
        w.z = f2bf(v.z * rn); w.w = f2bf(v.w * rn);
        *(ushort4*)(Bsh + r * LDB + f4 * 4) = w;
    }
    __syncthreads();

    // ---- per-wave 64x64 MFMA tile ----
    const int lane = t & 63;
    const int wv   = t >> 6;                   // 0..7
    const int quad = lane >> 4;                // 0..3
    const int sixt = lane & 15;
    const int mg = wv >> 2;                    // 0..1 : row half
    const int ng = wv & 3;                     // 0..3 : class quarter

    // A fragments: 4 m-subtiles x 2 k-steps, each lane 8 contiguous k at quad*8
    short8 af[4][2];
    #pragma unroll
    for (int ms = 0; ms < 4; ++ms) {
        int rowL = mg * 64 + ms * 16 + sixt;
        af[ms][0] = *(const short8*)(Ash + rowL * LDA + quad * 8);
        af[ms][1] = *(const short8*)(Ash + rowL * LDA + 32 + quad * 8);
    }
    // per-lane -2||x|| for the rows this lane sees in D-layout (row = quad*4+reg)
    float cw[4][4];
    #pragma unroll
    for (int ms = 0; ms < 4; ++ms)
        #pragma unroll
        for (int rg = 0; rg < 4; ++rg)
            cw[ms][rg] = crow[mg * 64 + ms * 16 + quad * 4 + rg];

    float s_acc[4][4];
    #pragma unroll
    for (int ms = 0; ms < 4; ++ms)
        #pragma unroll
        for (int rg = 0; rg < 4; ++rg) s_acc[ms][rg] = 0.f;

    #pragma unroll
    for (int ns = 0; ns < 4; ++ns) {
        int classL = ng * 64 + ns * 16 + sixt;
        short8 bf0 = *(const short8*)(Bsh + classL * LDB + quad * 8);
        short8 bf1 = *(const short8*)(Bsh + classL * LDB + 32 + quad * 8);
        #pragma unroll
        for (int ms = 0; ms < 4; ++ms) {
            f32x4 acc = {0.f, 0.f, 0.f, 0.f};
            acc = __builtin_amdgcn_mfma_f32_16x16x32_bf16(af[ms][0], bf0, acc, 0, 0, 0);
            acc = __builtin_amdgcn_mfma_f32_16x16x32_bf16(af[ms][1], bf1, acc, 0, 0, 0);
            // e = exp(2*acc - 2||x||): bounded by ~1, no running max needed
            #pragma unroll
            for (int rg = 0; rg < 4; ++rg)
                s_acc[ms][rg] += __expf(fmaf(2.0f, acc[rg], cw[ms][rg]));
        }
    }

    // reduce the 16 column-lanes within each quad, then store per-row partials
    #pragma unroll
    for (int ms = 0; ms < 4; ++ms)
        #pragma unroll
        for (int rg = 0; rg < 4; ++rg) {
            float s = s_acc[ms][rg];
            s += __shfl_xor(s, 1); s += __shfl_xor(s, 2);
            s += __shfl_xor(s, 4); s += __shfl_xor(s, 8);
            s_acc[ms][rg] = s;
        }
    if (sixt == 0) {
        #pragma unroll
        for (int ms = 0; ms < 4; ++ms)
            #pragma unroll
            for (int rg = 0; rg < 4; ++rg) {
                int row = row0 + mg * 64 + ms * 16 + quad * 4 + rg;
                ws[(size_t)row * PPR + ct * 4 + ng] = s_acc[ms][rg];
            }
    }
}

__global__ __launch_bounds__(256) void proxynca_reduce(
    const float* __restrict__ xs, const int* __restrict__ ys,
    const float* __restrict__ proxies, const float* __restrict__ ws,
    float* __restrict__ ps)
{
    const int lane = threadIdx.x & 63;
    const int row = blockIdx.x * 4 + (threadIdx.x >> 6);

    float x = xs[(size_t)row * D + lane];
    int y = ys[row];
    float p = proxies[(size_t)y * D + lane];

    float xx = x * x, pp = p * p;
    #pragma unroll
    for (int off = 1; off < 64; off <<= 1) {
        xx += __shfl_xor(xx, off);
        pp += __shfl_xor(pp, off);
    }
    float nx = sqrtf(xx);
    float rn = 1.0f / fmaxf(sqrtf(pp), 1e-12f);
    float ph = p * rn;

    float xp = x * ph;                       // exact fp32 dot for d_pos
    float xpb = bf_round(x) * bf_round(ph);  // bf16-matched dot for s subtraction
    #pragma unroll
    for (int off = 1; off < 64; off <<= 1) {
        xp  += __shfl_xor(xp, off);
        xpb += __shfl_xor(xpb, off);
    }

    float s = 0.f;
    for (int j = lane; j < PPR; j += 64) s += ws[(size_t)row * PPR + j];
    #pragma unroll
    for (int off = 1; off < 64; off <<= 1) s += __shfl_xor(s, off);

    if (lane == 0) {
        float cr = -2.0f * nx;
        float e_pos = __expf(fmaf(2.0f, xpb, cr));      // positive class term
        float e_pad = __expf(cr);                        // each zero pad row term
        float s_neg = s - e_pos - (float)CPAD * e_pad;
        // per_sample = d_pos + log(sum_neg exp(-dist)) = 2(||x|| - x.p_hat) + ln(s_neg)
        ps[row] = 2.0f * (nx - xp) + logf(s_neg);
    }
}

__global__ __launch_bounds__(1024) void proxynca_final(
    const float* __restrict__ ps, float* __restrict__ out)
{
    __shared__ float red[16];
    const int t = threadIdx.x;
    float v = ps[t];
    #pragma unroll
    for (int off = 1; off < 64; off <<= 1) v += __shfl_xor(v, off);
    if ((t & 63) == 0) red[t >> 6] = v;
    __syncthreads();
    if (t < 16) {
        float x = red[t];
        #pragma unroll
        for (int off = 1; off < 16; off <<= 1) x += __shfl_xor(x, off);
        if (t == 0) out[0] = x * (1.0f / B);
    }
}

extern "C" void kernel_launch(void* const* d_in, const int* in_sizes, int n_in,
                              void* d_out, int out_size, void* d_ws, size_t ws_size,
                              hipStream_t stream)
{
    const float* xs      = (const float*)d_in[0];
    const int*   ys      = (const int*)d_in[1];
    const float* proxies = (const float*)d_in[2];
    float* ws  = (float*)d_ws;
    float* out = (float*)d_out;
    float* ps  = ws + (size_t)B * PPR;

    dim3 gridA(B / MT, NCH);
    proxynca_main<<<gridA, 512, 0, stream>>>(xs, proxies, ws);
    proxynca_reduce<<<B / 4, 256, 0, stream>>>(xs, ys, proxies, ws, ps);
    proxynca_final<<<1, 1024, 0, stream>>>(ps, out);
}

// Round 3
// 122.299 us; speedup vs baseline: 2.9303x; 1.2024x over previous
//
#include <hip/hip_runtime.h>
#include <math.h>

#define B 1024
#define C 100000
#define D 64
#define MT 128                  // rows per block
#define TC 256                  // classes per block
#define NCH 391                 // ceil(C/TC); NCH*TC = 100096
#define NPADROWS (NCH * TC)     // 100096
#define CPAD (NPADROWS - C)     // 96 zero pad rows
#define PPR (NCH * 4)           // s-partials per row = 1564
#define L2E 1.4426950408889634f

typedef __attribute__((ext_vector_type(8))) short short8;
typedef __attribute__((ext_vector_type(4))) float f32x4;

// ws byte layout (total ~19.4 MB):
//   [0, B*PPR*4)        : s-partials float [row][part]
//   WS_CW2  (+4KB)      : cw2[row] = -2*||x_row||*log2e
//   WS_XBF  (+128KB)    : xs as bf16 [B][64]
//   WS_PBF  (+12.8MB)   : normalized proxies as bf16 [NPADROWS][64] (pad rows 0)
#define WS_PART 0
#define WS_CW2  ((size_t)B * PPR * 4)
#define WS_XBF  (WS_CW2 + B * 4)
#define WS_PBF  (WS_XBF + (size_t)B * D * 2)

#define GLB(p) ((const __attribute__((address_space(1))) void*)(p))
#define LDS(p) ((__attribute__((address_space(3))) void*)(p))

static __device__ __forceinline__ unsigned short f2bf(float f) {
    unsigned u = __float_as_uint(f);
    return (unsigned short)((u + 0x7fffu + ((u >> 16) & 1u)) >> 16);  // RNE
}
static __device__ __forceinline__ float bf_round(float f) {
    return __uint_as_float(((unsigned)f2bf(f)) << 16);
}
static __device__ __forceinline__ float fexp2(float x) {
#if __has_builtin(__builtin_amdgcn_exp2f)
    return __builtin_amdgcn_exp2f(x);
#else
    return __expf(x * 0.6931471805599453f);
#endif
}

// ---- prep: normalize proxies -> bf16 (pad rows zero); xs -> bf16; cw2 ----
__global__ __launch_bounds__(256) void proxynca_prep(
    const float* __restrict__ xs, const float* __restrict__ proxies,
    unsigned short* __restrict__ Xbf, unsigned short* __restrict__ Pbf,
    float* __restrict__ cw2)
{
    const int t = threadIdx.x;
    const int rl = t >> 4, f4 = t & 15;         // 16 lanes per row
    const int bb = blockIdx.x;
    if (bb < NPADROWS / 16) {
        int gr = bb * 16 + rl;
        float4 v = make_float4(0.f, 0.f, 0.f, 0.f);
        if (gr < C) v = *(const float4*)(proxies + (size_t)gr * D + f4 * 4);
        float ss = v.x*v.x + v.y*v.y + v.z*v.z + v.w*v.w;
        ss += __shfl_xor(ss, 1); ss += __shfl_xor(ss, 2);
        ss += __shfl_xor(ss, 4); ss += __shfl_xor(ss, 8);
        float rn = 1.0f / fmaxf(sqrtf(ss), 1e-12f);
        ushort4 w;
        w.x = f2bf(v.x * rn); w.y = f2bf(v.y * rn);
        w.z = f2bf(v.z * rn); w.w = f2bf(v.w * rn);
        *(ushort4*)(Pbf + (size_t)gr * D + f4 * 4) = w;
    } else {
        int row = (bb - NPADROWS / 16) * 16 + rl;   // 0..1023
        float4 v = *(const float4*)(xs + (size_t)row * D + f4 * 4);
        float ss = v.x*v.x + v.y*v.y + v.z*v.z + v.w*v.w;
        ss += __shfl_xor(ss, 1); ss += __shfl_xor(ss, 2);
        ss += __shfl_xor(ss, 4); ss += __shfl_xor(ss, 8);
        ushort4 w;
        w.x = f2bf(v.x); w.y = f2bf(v.y); w.z = f2bf(v.z); w.w = f2bf(v.w);
        *(ushort4*)(Xbf + (size_t)row * D + f4 * 4) = w;
        if (f4 == 0) cw2[row] = -2.0f * sqrtf(ss) * L2E;
    }
}

// ---- main: MFMA GEMM tile + fused exp2 epilogue ----
__global__ __launch_bounds__(512, 4) void proxynca_main(
    const unsigned short* __restrict__ Xbf, const unsigned short* __restrict__ Pbf,
    const float* __restrict__ cw2v, float* __restrict__ partial)
{
    __shared__ __align__(16) unsigned short Ash[MT * 64];   // 16 KB, XOR-swizzled
    __shared__ __align__(16) unsigned short Bsh[TC * 64];   // 32 KB, XOR-swizzled
    __shared__ float crow[MT];

    const int t = threadIdx.x;                 // 0..511
    const int lane = t & 63;
    const int wv = t >> 6;                     // 0..7
    const int row0 = blockIdx.x * MT;
    const int ct = blockIdx.y;

    const unsigned short* Asrc = Xbf + (size_t)row0 * D;
    const unsigned short* Bsrc = Pbf + (size_t)ct * TC * D;

    // A tile: 1024 16B-chunks, 2 rounds; source index XOR-swizzled so LDS
    // chunk (row, q) holds global chunk (row, q ^ (row&7)) (involution).
    #pragma unroll
    for (int j = 0; j < 2; ++j) {
        int c = (j * 8 + wv) * 64 + lane;
        int row = c >> 3, q = c & 7;
        int sc = (row << 3) | (q ^ (row & 7));
        __builtin_amdgcn_global_load_lds(GLB(Asrc + sc * 8),
            LDS(Ash + (size_t)(j * 8 + wv) * 512), 16, 0, 0);
    }
    // B tile: 2048 chunks, 4 rounds
    #pragma unroll
    for (int j = 0; j < 4; ++j) {
        int c = (j * 8 + wv) * 64 + lane;
        int row = c >> 3, q = c & 7;
        int sc = (row << 3) | (q ^ (row & 7));
        __builtin_amdgcn_global_load_lds(GLB(Bsrc + sc * 8),
            LDS(Bsh + (size_t)(j * 8 + wv) * 512), 16, 0, 0);
    }
    if (t < MT) crow[t] = cw2v[row0 + t];
    __syncthreads();

    const int quad = lane >> 4, sixt = lane & 15;
    const int mg = wv >> 2, ng = wv & 3;

    short8 af[4][2];
    #pragma unroll
    for (int ms = 0; ms < 4; ++ms) {
        int rowL = mg * 64 + ms * 16 + sixt;
        int sw = rowL & 7;
        af[ms][0] = *(const short8*)(Ash + (size_t)(((rowL << 3) | (quad ^ sw)) * 8));
        af[ms][1] = *(const short8*)(Ash + (size_t)(((rowL << 3) | ((4 + quad) ^ sw)) * 8));
    }
    float cw[4][4];
    #pragma unroll
    for (int ms = 0; ms < 4; ++ms)
        #pragma unroll
        for (int rg = 0; rg < 4; ++rg)
            cw[ms][rg] = crow[mg * 64 + ms * 16 + quad * 4 + rg];

    float s_acc[4][4];
    #pragma unroll
    for (int ms = 0; ms < 4; ++ms)
        #pragma unroll
        for (int rg = 0; rg < 4; ++rg) s_acc[ms][rg] = 0.f;

    #pragma unroll
    for (int ns = 0; ns < 4; ++ns) {
        int classL = ng * 64 + ns * 16 + sixt;
        int sw = classL & 7;
        short8 b0 = *(const short8*)(Bsh + (size_t)(((classL << 3) | (quad ^ sw)) * 8));
        short8 b1 = *(const short8*)(Bsh + (size_t)(((classL << 3) | ((4 + quad) ^ sw)) * 8));
        #pragma unroll
        for (int ms = 0; ms < 4; ++ms) {
            f32x4 acc = {0.f, 0.f, 0.f, 0.f};
            acc = __builtin_amdgcn_mfma_f32_16x16x32_bf16(af[ms][0], b0, acc, 0, 0, 0);
            acc = __builtin_amdgcn_mfma_f32_16x16x32_bf16(af[ms][1], b1, acc, 0, 0, 0);
            // e^{-dist} * e^{(||x||-1)^2} = 2^(2*l2e*acc + cw2); bounded by ~1
            #pragma unroll
            for (int rg = 0; rg < 4; ++rg)
                s_acc[ms][rg] += fexp2(fmaf(2.0f * L2E, acc[rg], cw[ms][rg]));
        }
    }

    #pragma unroll
    for (int ms = 0; ms < 4; ++ms)
        #pragma unroll
        for (int rg = 0; rg < 4; ++rg) {
            float s = s_acc[ms][rg];
            s += __shfl_xor(s, 1); s += __shfl_xor(s, 2);
            s += __shfl_xor(s, 4); s += __shfl_xor(s, 8);
            s_acc[ms][rg] = s;
        }
    if (sixt == 0) {
        #pragma unroll
        for (int ms = 0; ms < 4; ++ms)
            #pragma unroll
            for (int rg = 0; rg < 4; ++rg) {
                int row = row0 + mg * 64 + ms * 16 + quad * 4 + rg;
                partial[(size_t)row * PPR + ct * 4 + ng] = s_acc[ms][rg];
            }
    }
}

// ---- reduce + final mean (atomicAdd into zeroed d_out) ----
__global__ __launch_bounds__(256) void proxynca_reduce(
    const float* __restrict__ xs, const int* __restrict__ ys,
    const float* __restrict__ proxies, const float* __restrict__ partial,
    float* __restrict__ out)
{
    __shared__ float acc4[4];
    const int lane = threadIdx.x & 63;
    const int w = threadIdx.x >> 6;
    const int row = blockIdx.x * 4 + w;

    float x = xs[(size_t)row * D + lane];
    int y = ys[row];
    float p = proxies[(size_t)y * D + lane];

    float xx = x * x, pp = p * p;
    #pragma unroll
    for (int off = 1; off < 64; off <<= 1) {
        xx += __shfl_xor(xx, off);
        pp += __shfl_xor(pp, off);
    }
    float nx = sqrtf(xx);
    float rn = 1.0f / fmaxf(sqrtf(pp), 1e-12f);
    float ph = p * rn;

    float xp = x * ph;                       // exact fp32 dot for d_pos
    float xpb = bf_round(x) * bf_round(ph);  // bf16-matched dot for s subtraction
    #pragma unroll
    for (int off = 1; off < 64; off <<= 1) {
        xp  += __shfl_xor(xp, off);
        xpb += __shfl_xor(xpb, off);
    }

    float s = 0.f;
    for (int j = lane; j < PPR; j += 64) s += partial[(size_t)row * PPR + j];
    #pragma unroll
    for (int off = 1; off < 64; off <<= 1) s += __shfl_xor(s, off);

    if (lane == 0) {
        float cw2r = -2.0f * nx * L2E;
        float e_pos = fexp2(fmaf(2.0f * L2E, xpb, cw2r));   // positive class term
        float e_pad = fexp2(cw2r);                          // each zero pad row
        float s_neg = s - e_pos - (float)CPAD * e_pad;
        acc4[w] = 2.0f * (nx - xp) + logf(s_neg);
    }
    __syncthreads();
    if (threadIdx.x == 0) {
        float v = acc4[0] + acc4[1] + acc4[2] + acc4[3];
        atomicAdd(out, v * (1.0f / (float)B));
    }
}

extern "C" void kernel_launch(void* const* d_in, const int* in_sizes, int n_in,
                              void* d_out, int out_size, void* d_ws, size_t ws_size,
                              hipStream_t stream)
{
    const float* xs      = (const float*)d_in[0];
    const int*   ys      = (const int*)d_in[1];
    const float* proxies = (const float*)d_in[2];
    char* ws = (char*)d_ws;
    float* partial = (float*)(ws + WS_PART);
    float* cw2     = (float*)(ws + WS_CW2);
    unsigned short* Xbf = (unsigned short*)(ws + WS_XBF);
    unsigned short* Pbf = (unsigned short*)(ws + WS_PBF);
    float* out = (float*)d_out;

    hipMemsetAsync(out, 0, sizeof(float), stream);
    proxynca_prep<<<NPADROWS / 16 + B / 16, 256, 0, stream>>>(xs, proxies, Xbf, Pbf, cw2);
    dim3 gridA(B / MT, NCH);
    proxynca_main<<<gridA, 512, 0, stream>>>(Xbf, Pbf, cw2, partial);
    proxynca_reduce<<<B / 4, 256, 0, stream>>>(xs, ys, proxies, partial, out);
}